// Round 1
// baseline (1426.384 us; speedup 1.0000x reference)
//
#include <hip/hip_runtime.h>
#include <cfloat>

// ---------------------------------------------------------------------------
// DGCNN-like model on MI355X, fp32 (CDNA4 has no fp32 MFMA -> VALU GEMMs).
// Pipeline:
//   knn1 (3-dim, exact, k=10) -> idx1
//   pre1: v1[m]=w1a.p, u1[n]=(w1b-w1a).p        (edge conv decomposition)
//   edge1: h1=mish(bn(v1[m]+u1[n])); h2=mish(bn(W2 h1)); x1=max_k  -> cat[:,0:64], xx2
//   pre3 GEMM: [v3|u3] = x1 @ w3stack^T
//   knn2 (64-dim, exact) -> idx2
//   edge2: like edge1 with W4 -> x2 -> cat[:,64:128]
//   GEMM6: mish(bn(cat@w6^T)) -> column max only (flipped-uint atomics)
//   bias7: per-batch bias = (w7[:, :1024]@gmax)*s7 + sh7
//   GEMM7: mish(cat@w7x^T * s7 + bias7) -> h7
//   GEMM8: mish(bn(h7@w8^T)) -> h8
//   out:   h8@w9^T -> [B,2,N]
// ---------------------------------------------------------------------------

#define BN_EPS 1e-5f

__device__ __forceinline__ float mish_f(float x) {
  // mish(x) = x*tanh(softplus(x)) = x*(e^2+2e)/(e^2+2e+2), e=exp(x)
  float e = __expf(x);
  float num = e * (e + 2.0f);
  float r = x * (num / (num + 2.0f));
  return (x > 44.0f) ? x : r;   // guard e^2 overflow; below 44 exact formula
}

__device__ __forceinline__ float rl_f(float v, int l) {
  return __uint_as_float((unsigned)__builtin_amdgcn_readlane((int)__float_as_uint(v), l));
}

// monotonic float<->uint encode for atomicMax on possibly-negative floats
__device__ __forceinline__ unsigned enc_f(float f) {
  unsigned b = __float_as_uint(f);
  return (b & 0x80000000u) ? ~b : (b | 0x80000000u);
}
__device__ __forceinline__ float dec_f(unsigned u) {
  unsigned b = (u & 0x80000000u) ? (u ^ 0x80000000u) : ~u;
  return __uint_as_float(b);
}

// sorted-descending top-10 insertion; ties keep earlier (smaller) index first.
__device__ __forceinline__ void topk_insert(float (&v)[10], int (&id)[10], float nd, int m) {
  if (nd > v[9]) {
    v[9] = nd; id[9] = m;
#pragma unroll
    for (int j = 9; j > 0; --j) {
      if (v[j] > v[j - 1]) {
        float tv = v[j]; v[j] = v[j - 1]; v[j - 1] = tv;
        int ti = id[j]; id[j] = id[j - 1]; id[j - 1] = ti;
      }
    }
  }
}

// ---------------------------------------------------------------------------
// knn1: 3-dim points, whole batch point cloud in LDS. 64 rows/block, each row
// handled by a quad (4 lanes), each sub-lane scans 1024 candidates, then
// quad-merge of sorted lists via shfl_xor(1,2).
// ---------------------------------------------------------------------------
__global__ __launch_bounds__(256) void knn1_k(const float* __restrict__ x, int* __restrict__ idx1) {
  __shared__ float pls[3][4100];  // 4 chunks of 1025 (pad breaks bank aliasing)
  const int tid = threadIdx.x;
  const int rowBase = blockIdx.x * 64;
  const int b = rowBase >> 12;
  const float* xb = x + (size_t)b * 3 * 4096;
#pragma unroll
  for (int c = 0; c < 3; ++c) {
#pragma unroll
    for (int s = 0; s < 16; ++s) {
      int li = tid + 256 * s;
      pls[c][(li >> 10) * 1025 + (li & 1023)] = xb[c * 4096 + li];
    }
  }
  __syncthreads();
  const int sub = tid & 3;
  const int nloc = (rowBase & 4095) + (tid >> 2);
  float pnx = xb[nloc], pny = xb[4096 + nloc], pnz = xb[8192 + nloc];
  float xxn = pnx * pnx; xxn = fmaf(pny, pny, xxn); xxn = fmaf(pnz, pnz, xxn);
  float v[10]; int id[10];
#pragma unroll
  for (int j = 0; j < 10; ++j) { v[j] = -FLT_MAX; id[j] = -1; }
  const int base = sub * 1025;
  for (int i = 0; i < 1024; ++i) {
    float mx = pls[0][base + i], my = pls[1][base + i], mz = pls[2][base + i];
    float in = mx * pnx; in = fmaf(my, pny, in); in = fmaf(mz, pnz, in);
    float xm = mx * mx;  xm = fmaf(my, my, xm);  xm = fmaf(mz, mz, xm);
    float nd = 2.0f * in - xxn - xm;   // == 0 exactly for self (same fma chains)
    topk_insert(v, id, nd, sub * 1024 + i);
  }
  int k0 = -1, k1 = -1, k2 = -1;
#pragma unroll
  for (int r = 0; r < 10; ++r) {
    float mv = v[0]; int mi = id[0];
    { float ov = __shfl_xor(mv, 1); int oi = __shfl_xor(mi, 1);
      if (ov > mv || (ov == mv && oi < mi)) { mv = ov; mi = oi; } }
    { float ov = __shfl_xor(mv, 2); int oi = __shfl_xor(mi, 2);
      if (ov > mv || (ov == mv && oi < mi)) { mv = ov; mi = oi; } }
    if (id[0] == mi) {
#pragma unroll
      for (int j = 0; j < 9; ++j) { v[j] = v[j + 1]; id[j] = id[j + 1]; }
      v[9] = -FLT_MAX; id[9] = -1;
    }
    if ((r & 3) == sub) { if (r < 4) k0 = mi; else if (r < 8) k1 = mi; else k2 = mi; }
  }
  const int obase = (rowBase + (tid >> 2)) * 10;
  if (sub == 0)      { idx1[obase + 0] = k0; idx1[obase + 4] = k1; idx1[obase + 8] = k2; }
  else if (sub == 1) { idx1[obase + 1] = k0; idx1[obase + 5] = k1; idx1[obase + 9] = k2; }
  else if (sub == 2) { idx1[obase + 2] = k0; idx1[obase + 6] = k1; }
  else               { idx1[obase + 3] = k0; idx1[obase + 7] = k1; }
}

// ---------------------------------------------------------------------------
// pre1: per-point v1[m][c] = w1a[c].p,  u1[n][c] = (w1b[c]-w1a[c]).p
// ---------------------------------------------------------------------------
__global__ __launch_bounds__(256) void pre1_k(const float* __restrict__ x, const float* __restrict__ w1,
                                              float* __restrict__ e1m, float* __restrict__ e1n) {
  int gt = blockIdx.x * 256 + threadIdx.x;
  int pt = gt >> 6, c = gt & 63;
  int b = pt >> 12, n = pt & 4095;
  const float* xb = x + (size_t)b * 3 * 4096;
  float px = xb[n], py = xb[4096 + n], pz = xb[8192 + n];
  const float* wr = w1 + c * 6;
  float a0 = wr[0], a1 = wr[1], a2 = wr[2], b0 = wr[3], b1 = wr[4], b2 = wr[5];
  float vm = a0 * px; vm = fmaf(a1, py, vm); vm = fmaf(a2, pz, vm);
  float un = (b0 - a0) * px; un = fmaf(b1 - a1, py, un); un = fmaf(b2 - a2, pz, un);
  e1m[(size_t)pt * 64 + c] = vm;
  e1n[(size_t)pt * 64 + c] = un;
}

// ---------------------------------------------------------------------------
// edge conv: per wave one row; lane = output channel.
// h1 = mish(bn1(vm[m]+un[n])); h2 = mish(bn2(W h1)); out = max over k=10.
// 64x64 matvec via readlane broadcast (W row cached in 16 float4 regs).
// ---------------------------------------------------------------------------
template <bool WRITE_XX>
__global__ __launch_bounds__(256) void edge_k(
    const int* __restrict__ idx,
    const float* __restrict__ vm, const float* __restrict__ un, int stride,
    const float* __restrict__ w,
    const float* __restrict__ ga, const float* __restrict__ ba, const float* __restrict__ ma, const float* __restrict__ va,
    const float* __restrict__ gb, const float* __restrict__ bb, const float* __restrict__ mb, const float* __restrict__ vb,
    float* __restrict__ outCat, int outOff, float* __restrict__ xxOut) {
  const int tid = threadIdx.x;
  const int wid = tid >> 6, lane = tid & 63;
  const int r = blockIdx.x * 4 + wid;
  const int mbase = (r >> 12) << 12;
  float4 wv[16];
  const float4* wp = (const float4*)(w + lane * 64);
#pragma unroll
  for (int i = 0; i < 16; ++i) wv[i] = wp[i];
  float s1 = ga[lane] * rsqrtf(va[lane] + BN_EPS); float t1 = ba[lane] - ma[lane] * s1;
  float s2 = gb[lane] * rsqrtf(vb[lane] + BN_EPS); float t2 = bb[lane] - mb[lane] * s2;
  float uc = un[(size_t)r * stride + lane];
  float best = -FLT_MAX;
#pragma unroll
  for (int kk = 0; kk < 10; ++kk) {
    int m = idx[r * 10 + kk];
    float pre = vm[(size_t)(mbase + m) * stride + lane] + uc;
    float h1 = mish_f(fmaf(pre, s1, t1));
    float acc = 0.f;
#pragma unroll
    for (int j4 = 0; j4 < 16; ++j4) {
      float4 wq = wv[j4];
      acc = fmaf(wq.x, rl_f(h1, 4 * j4 + 0), acc);
      acc = fmaf(wq.y, rl_f(h1, 4 * j4 + 1), acc);
      acc = fmaf(wq.z, rl_f(h1, 4 * j4 + 2), acc);
      acc = fmaf(wq.w, rl_f(h1, 4 * j4 + 3), acc);
    }
    float h2 = mish_f(fmaf(acc, s2, t2));
    best = fmaxf(best, h2);
  }
  outCat[(size_t)r * 128 + outOff + lane] = best;
  if (WRITE_XX) {
    float q = best * best;
#pragma unroll
    for (int o = 1; o < 64; o <<= 1) q += __shfl_xor(q, o);
    if (lane == 0) xxOut[r] = q;
  }
}

// ---------------------------------------------------------------------------
// knn2: 64-dim exact knn over cat[:,0:64] (=x1). Wave handles 2 rows (query
// vecs in 32 float4 regs); candidate tiles 128x64 in LDS, XOR-rotated f4 slots
// so ds_read_b128 is phase-conflict-free. Fused per-lane top-10 + wave merge.
// ---------------------------------------------------------------------------
__global__ __launch_bounds__(256, 2) void knn2_k(const float* __restrict__ cat,
                                                 const float* __restrict__ xx2, int* __restrict__ idx2) {
  __shared__ float tile[128 * 64];
  __shared__ float xxm[128];
  const int tid = threadIdx.x;
  const int wid = tid >> 6, lane = tid & 63;
  const int r0 = blockIdx.x * 8 + wid * 2;
  const int nbase = (r0 >> 12) << 12;
  float4 xa[16], xb4[16];
  const float4* pa = (const float4*)(cat + (size_t)r0 * 128);
  const float4* pb = (const float4*)(cat + (size_t)(r0 + 1) * 128);
#pragma unroll
  for (int s = 0; s < 16; ++s) { xa[s] = pa[s]; xb4[s] = pb[s]; }
  float xxA = xx2[r0], xxB = xx2[r0 + 1];
  float vA[10], vB[10]; int iA[10], iB[10];
#pragma unroll
  for (int j = 0; j < 10; ++j) { vA[j] = -FLT_MAX; vB[j] = -FLT_MAX; iA[j] = -1; iB[j] = -1; }
  for (int t = 0; t < 32; ++t) {
    __syncthreads();
#pragma unroll
    for (int s = 0; s < 8; ++s) {
      int fi = tid + 256 * s;
      int m = fi >> 4, c4 = fi & 15;
      float4 val = *(const float4*)(cat + (size_t)(nbase + t * 128 + m) * 128 + c4 * 4);
      int slot = (c4 + m) & 15;
      *(float4*)(tile + m * 64 + slot * 4) = val;
    }
    if (tid < 128) xxm[tid] = xx2[nbase + t * 128 + tid];
    __syncthreads();
#pragma unroll
    for (int cb = 0; cb < 2; ++cb) {
      int ml = cb * 64 + lane;
      const float* trow = tile + ml * 64;
      float aA = 0.f, aB = 0.f;
#pragma unroll
      for (int c4 = 0; c4 < 16; ++c4) {
        int slot = (c4 + ml) & 15;
        float4 tv = *(const float4*)(trow + slot * 4);
        aA = fmaf(tv.x, xa[c4].x, aA); aA = fmaf(tv.y, xa[c4].y, aA);
        aA = fmaf(tv.z, xa[c4].z, aA); aA = fmaf(tv.w, xa[c4].w, aA);
        aB = fmaf(tv.x, xb4[c4].x, aB); aB = fmaf(tv.y, xb4[c4].y, aB);
        aB = fmaf(tv.z, xb4[c4].z, aB); aB = fmaf(tv.w, xb4[c4].w, aB);
      }
      int m = t * 128 + ml;
      float xm = xxm[ml];
      topk_insert(vA, iA, 2.0f * aA - xxA - xm, m);
      topk_insert(vB, iB, 2.0f * aB - xxB - xm, m);
    }
  }
  int keepA = -1, keepB = -1;
#pragma unroll
  for (int rr = 0; rr < 10; ++rr) {
    float mv = vA[0]; int mi = iA[0];
#pragma unroll
    for (int o = 1; o < 64; o <<= 1) {
      float ov = __shfl_xor(mv, o); int oi = __shfl_xor(mi, o);
      if (ov > mv || (ov == mv && oi < mi)) { mv = ov; mi = oi; }
    }
    if (iA[0] == mi) {
#pragma unroll
      for (int j = 0; j < 9; ++j) { vA[j] = vA[j + 1]; iA[j] = iA[j + 1]; }
      vA[9] = -FLT_MAX; iA[9] = -1;
    }
    if (lane == rr) keepA = mi;
  }
#pragma unroll
  for (int rr = 0; rr < 10; ++rr) {
    float mv = vB[0]; int mi = iB[0];
#pragma unroll
    for (int o = 1; o < 64; o <<= 1) {
      float ov = __shfl_xor(mv, o); int oi = __shfl_xor(mi, o);
      if (ov > mv || (ov == mv && oi < mi)) { mv = ov; mi = oi; }
    }
    if (iB[0] == mi) {
#pragma unroll
      for (int j = 0; j < 9; ++j) { vB[j] = vB[j + 1]; iB[j] = iB[j + 1]; }
      vB[9] = -FLT_MAX; iB[9] = -1;
    }
    if (lane == rr) keepB = mi;
  }
  if (lane < 10) {
    idx2[r0 * 10 + lane] = keepA;
    idx2[(r0 + 1) * 10 + lane] = keepB;
  }
}

// ---------------------------------------------------------------------------
// w3stack: rows 0..63 = w3[:, :64]; rows 64..127 = w3[:, 64:] - w3[:, :64]
// ---------------------------------------------------------------------------
__global__ void w3s_k(const float* __restrict__ w3, float* __restrict__ w3s) {
  int t = blockIdx.x * 256 + threadIdx.x;  // 0..8191
  int c = t >> 6, k = t & 63;
  float v;
  if (c < 64) v = w3[c * 128 + k];
  else { int cc = c - 64; v = w3[cc * 128 + 64 + k] - w3[cc * 128 + k]; }
  w3s[t] = v;
}

// ---------------------------------------------------------------------------
// fp32 VALU GEMM:  C[M][N] = epi(A[M][lda(:K)] @ W[N][ldw(:K)]^T)
// BM=64*QM, BN=64*QN, BK=16; 256 threads; per-thread (4*QM)x(4*QN) microtile.
// EPI: 0 raw store | 1 bn+mish store | 2 bn+mish column-max (no store)
//    | 3 scale*acc + per-batch bias + mish store
// ---------------------------------------------------------------------------
template <int QM, int QN, int EPI>
__global__ __launch_bounds__(256) void gemm_k(
    const float* __restrict__ A, int lda,
    const float* __restrict__ W, int ldw,
    float* __restrict__ C, int ldc, int K, int Ntot,
    const float* __restrict__ eg, const float* __restrict__ eb,
    const float* __restrict__ em, const float* __restrict__ ev,
    const float* __restrict__ pbBias, unsigned int* __restrict__ gmaxOut) {
  constexpr int BM = 64 * QM, BN = 64 * QN;
  __shared__ float aL[16][BM];
  __shared__ float bL[16][BN];
  __shared__ unsigned int cm[BN];
  const int tid = threadIdx.x;
  const int tm = tid >> 4, tn = tid & 15;
  const int rowBase = blockIdx.x * BM;
  const int colBase = blockIdx.y * BN;
  float acc[QM][QN][4][4] = {};
  if (EPI == 2 && tid < BN) cm[tid] = 0u;
  const int nkt = K >> 4;
  for (int kt = 0; kt < nkt; ++kt) {
#pragma unroll
    for (int s = 0; s < QM; ++s) {
      int fi = tid + 256 * s;
      int m = fi >> 2, k4 = fi & 3;
      float4 t4 = *(const float4*)(A + (size_t)(rowBase + m) * lda + (kt << 4) + k4 * 4);
      aL[k4 * 4 + 0][m] = t4.x; aL[k4 * 4 + 1][m] = t4.y;
      aL[k4 * 4 + 2][m] = t4.z; aL[k4 * 4 + 3][m] = t4.w;
    }
#pragma unroll
    for (int s = 0; s < QN; ++s) {
      int fi = tid + 256 * s;
      int n = fi >> 2, k4 = fi & 3;
      float4 t4 = *(const float4*)(W + (size_t)(colBase + n) * ldw + (kt << 4) + k4 * 4);
      bL[k4 * 4 + 0][n] = t4.x; bL[k4 * 4 + 1][n] = t4.y;
      bL[k4 * 4 + 2][n] = t4.z; bL[k4 * 4 + 3][n] = t4.w;
    }
    __syncthreads();
#pragma unroll
    for (int k = 0; k < 16; ++k) {
      float ar[QM][4], br[QN][4];
#pragma unroll
      for (int q = 0; q < QM; ++q) {
        float4 t4 = *(const float4*)&aL[k][q * 64 + tm * 4];
        ar[q][0] = t4.x; ar[q][1] = t4.y; ar[q][2] = t4.z; ar[q][3] = t4.w;
      }
#pragma unroll
      for (int q = 0; q < QN; ++q) {
        float4 t4 = *(const float4*)&bL[k][q * 64 + tn * 4];
        br[q][0] = t4.x; br[q][1] = t4.y; br[q][2] = t4.z; br[q][3] = t4.w;
      }
#pragma unroll
      for (int qm = 0; qm < QM; ++qm)
#pragma unroll
        for (int qn = 0; qn < QN; ++qn)
#pragma unroll
          for (int i = 0; i < 4; ++i)
#pragma unroll
            for (int j = 0; j < 4; ++j)
              acc[qm][qn][i][j] = fmaf(ar[qm][i], br[qn][j], acc[qm][qn][i][j]);
    }
    __syncthreads();
  }
  if (EPI == 0) {
#pragma unroll
    for (int qm = 0; qm < QM; ++qm)
#pragma unroll
      for (int i = 0; i < 4; ++i) {
        int row = rowBase + qm * 64 + tm * 4 + i;
#pragma unroll
        for (int qn = 0; qn < QN; ++qn) {
          float4 o;
          o.x = acc[qm][qn][i][0]; o.y = acc[qm][qn][i][1];
          o.z = acc[qm][qn][i][2]; o.w = acc[qm][qn][i][3];
          *(float4*)(C + (size_t)row * ldc + colBase + qn * 64 + tn * 4) = o;
        }
      }
  } else {
    const int bidx = rowBase >> 12;
    float sc[QN][4], sh[QN][4];
#pragma unroll
    for (int qn = 0; qn < QN; ++qn)
#pragma unroll
      for (int j = 0; j < 4; ++j) {
        int cg = colBase + qn * 64 + tn * 4 + j;
        float s = eg[cg] * rsqrtf(ev[cg] + BN_EPS);
        sc[qn][j] = s;
        sh[qn][j] = (EPI == 3) ? pbBias[bidx * Ntot + cg] : (eb[cg] - em[cg] * s);
      }
    if (EPI == 2) {
      float cmax[QN][4];
#pragma unroll
      for (int qn = 0; qn < QN; ++qn)
#pragma unroll
        for (int j = 0; j < 4; ++j) cmax[qn][j] = -FLT_MAX;
#pragma unroll
      for (int qm = 0; qm < QM; ++qm)
#pragma unroll
        for (int qn = 0; qn < QN; ++qn)
#pragma unroll
          for (int i = 0; i < 4; ++i)
#pragma unroll
            for (int j = 0; j < 4; ++j) {
              float vv = mish_f(fmaf(acc[qm][qn][i][j], sc[qn][j], sh[qn][j]));
              cmax[qn][j] = fmaxf(cmax[qn][j], vv);
            }
#pragma unroll
      for (int qn = 0; qn < QN; ++qn)
#pragma unroll
        for (int j = 0; j < 4; ++j)
          atomicMax(&cm[qn * 64 + tn * 4 + j], enc_f(cmax[qn][j]));
      __syncthreads();
      if (tid < BN) atomicMax(&gmaxOut[bidx * Ntot + colBase + tid], cm[tid]);
    } else {
#pragma unroll
      for (int qm = 0; qm < QM; ++qm)
#pragma unroll
        for (int i = 0; i < 4; ++i) {
          int row = rowBase + qm * 64 + tm * 4 + i;
#pragma unroll
          for (int qn = 0; qn < QN; ++qn) {
            float4 o;
            o.x = mish_f(fmaf(acc[qm][qn][i][0], sc[qn][0], sh[qn][0]));
            o.y = mish_f(fmaf(acc[qm][qn][i][1], sc[qn][1], sh[qn][1]));
            o.z = mish_f(fmaf(acc[qm][qn][i][2], sc[qn][2], sh[qn][2]));
            o.w = mish_f(fmaf(acc[qm][qn][i][3], sc[qn][3], sh[qn][3]));
            *(float4*)(C + (size_t)row * ldc + colBase + qn * 64 + tn * 4) = o;
          }
        }
    }
  }
}

// ---------------------------------------------------------------------------
// bias7: per-batch channel bias = (w7[:, :1024] @ gmax[b])*s7 + sh7
// ---------------------------------------------------------------------------
__global__ __launch_bounds__(256) void bias7_k(const unsigned int* __restrict__ gmaxU,
                                               const float* __restrict__ w7,
                                               const float* __restrict__ g7, const float* __restrict__ b7,
                                               const float* __restrict__ m7, const float* __restrict__ v7,
                                               float* __restrict__ bias7) {
  __shared__ float gl[1024];
  const int tid = threadIdx.x;
  const int batch = blockIdx.x >> 1, half = blockIdx.x & 1;
#pragma unroll
  for (int s = 0; s < 4; ++s) gl[tid + 256 * s] = dec_f(gmaxU[batch * 1024 + tid + 256 * s]);
  __syncthreads();
  const int ch = half * 256 + tid;
  const float4* wr = (const float4*)(w7 + (size_t)ch * 1152);
  float acc = 0.f;
  for (int j4 = 0; j4 < 256; ++j4) {
    float4 w = wr[j4];
    float4 g = *(const float4*)&gl[j4 * 4];
    acc = fmaf(w.x, g.x, acc); acc = fmaf(w.y, g.y, acc);
    acc = fmaf(w.z, g.z, acc); acc = fmaf(w.w, g.w, acc);
  }
  float s7 = g7[ch] * rsqrtf(v7[ch] + BN_EPS);
  bias7[batch * 512 + ch] = acc * s7 + (b7[ch] - m7[ch] * s7);
}

// ---------------------------------------------------------------------------
// out: out[b][o][n] = sum_c h8[row][c]*w9[o][c]
// ---------------------------------------------------------------------------
__global__ __launch_bounds__(256) void out_k(const float* __restrict__ h8,
                                             const float* __restrict__ w9, float* __restrict__ out) {
  __shared__ float w9l[512];
  const int tid = threadIdx.x;
  w9l[tid] = w9[tid];
  w9l[256 + tid] = w9[256 + tid];
  __syncthreads();
  const int t = blockIdx.x * 256 + tid;
  const int b = t >> 12, n = t & 4095;
  const float4* hr = (const float4*)(h8 + (size_t)t * 256);
  float a0 = 0.f, a1 = 0.f;
#pragma unroll
  for (int j4 = 0; j4 < 64; ++j4) {
    float4 h = hr[j4];
    float4 wa = *(const float4*)&w9l[j4 * 4];
    float4 wb = *(const float4*)&w9l[256 + j4 * 4];
    a0 = fmaf(h.x, wa.x, a0); a0 = fmaf(h.y, wa.y, a0);
    a0 = fmaf(h.z, wa.z, a0); a0 = fmaf(h.w, wa.w, a0);
    a1 = fmaf(h.x, wb.x, a1); a1 = fmaf(h.y, wb.y, a1);
    a1 = fmaf(h.z, wb.z, a1); a1 = fmaf(h.w, wb.w, a1);
  }
  out[(size_t)b * 8192 + n] = a0;
  out[(size_t)b * 8192 + 4096 + n] = a1;
}

// ---------------------------------------------------------------------------
extern "C" void kernel_launch(void* const* d_in, const int* in_sizes, int n_in,
                              void* d_out, int out_size, void* d_ws, size_t ws_size,
                              hipStream_t stream) {
  const float* x  = (const float*)d_in[0];
  const float* w1 = (const float*)d_in[1];
  const float* g1 = (const float*)d_in[2];
  const float* b1 = (const float*)d_in[3];
  const float* m1 = (const float*)d_in[4];
  const float* v1 = (const float*)d_in[5];
  const float* w2 = (const float*)d_in[6];
  const float* g2 = (const float*)d_in[7];
  const float* b2 = (const float*)d_in[8];
  const float* m2 = (const float*)d_in[9];
  const float* v2 = (const float*)d_in[10];
  const float* w3 = (const float*)d_in[11];
  const float* g3 = (const float*)d_in[12];
  const float* b3 = (const float*)d_in[13];
  const float* m3 = (const float*)d_in[14];
  const float* v3 = (const float*)d_in[15];
  const float* w4 = (const float*)d_in[16];
  const float* g4 = (const float*)d_in[17];
  const float* b4 = (const float*)d_in[18];
  const float* m4 = (const float*)d_in[19];
  const float* v4 = (const float*)d_in[20];
  const float* w6 = (const float*)d_in[21];
  const float* g6 = (const float*)d_in[22];
  const float* b6 = (const float*)d_in[23];
  const float* m6 = (const float*)d_in[24];
  const float* v6 = (const float*)d_in[25];
  const float* w7 = (const float*)d_in[26];
  const float* g7 = (const float*)d_in[27];
  const float* b7 = (const float*)d_in[28];
  const float* m7 = (const float*)d_in[29];
  const float* v7 = (const float*)d_in[30];
  const float* w8 = (const float*)d_in[31];
  const float* g8 = (const float*)d_in[32];
  const float* b8 = (const float*)d_in[33];
  const float* m8 = (const float*)d_in[34];
  const float* v8 = (const float*)d_in[35];
  const float* w9 = (const float*)d_in[36];

  float* ws = (float*)d_ws;
  // element offsets (all multiples of 4 -> 16B aligned)
  int* idx1       = (int*)(ws + 0);          //   163840
  int* idx2       = (int*)(ws + 163840);     //   163840
  float* xx2      = ws + 327680;             //    16384
  unsigned* gmax  = (unsigned*)(ws + 344064);//     4096
  float* bias7    = ws + 348160;             //     2048
  float* w3s      = ws + 350208;             //     8192
  float* e1n      = ws + 358400;             //  1048576
  float* e1m      = ws + 1406976;            //  1048576
  float* pre3     = ws + 358400;             //  2097152 (aliases e1n/e1m; written after edge1)
  float* cat      = ws + 2455552;            //  2097152
  float* h7       = ws + 4552704;            //  8388608
  float* h8       = ws + 12941312;           //  4194304  (end: 17135616 floats = 68.5 MB)

  hipMemsetAsync(gmax, 0, 4096 * sizeof(unsigned), stream);

  knn1_k<<<256, 256, 0, stream>>>(x, idx1);
  pre1_k<<<4096, 256, 0, stream>>>(x, w1, e1m, e1n);
  edge_k<true><<<4096, 256, 0, stream>>>(idx1, e1m, e1n, 64, w2,
                                         g1, b1, m1, v1, g2, b2, m2, v2,
                                         cat, 0, xx2);
  w3s_k<<<32, 256, 0, stream>>>(w3, w3s);
  gemm_k<1, 2, 0><<<dim3(256, 1), 256, 0, stream>>>(cat, 128, w3s, 64, pre3, 128, 64, 0,
                                                    nullptr, nullptr, nullptr, nullptr, nullptr, nullptr);
  knn2_k<<<2048, 256, 0, stream>>>(cat, xx2, idx2);
  edge_k<false><<<4096, 256, 0, stream>>>(idx2, pre3, pre3 + 64, 128, w4,
                                          g3, b3, m3, v3, g4, b4, m4, v4,
                                          cat, 64, nullptr);
  gemm_k<2, 2, 2><<<dim3(128, 8), 256, 0, stream>>>(cat, 128, w6, 128, nullptr, 0, 128, 1024,
                                                    g6, b6, m6, v6, nullptr, gmax);
  bias7_k<<<8, 256, 0, stream>>>(gmax, w7, g7, b7, m7, v7, bias7);
  gemm_k<2, 2, 3><<<dim3(128, 4), 256, 0, stream>>>(cat, 128, w7 + 1024, 1152, h7, 512, 128, 512,
                                                    g7, nullptr, nullptr, v7, bias7, nullptr);
  gemm_k<1, 2, 1><<<dim3(256, 2), 256, 0, stream>>>(h7, 512, w8, 512, h8, 256, 512, 256,
                                                    g8, b8, m8, v8, nullptr, nullptr);
  out_k<<<64, 256, 0, stream>>>(h8, w9, (float*)d_out);
}

// Round 2
// 1045.830 us; speedup vs baseline: 1.3639x; 1.3639x over previous
//
#include <hip/hip_runtime.h>
#include <cfloat>

// ---------------------------------------------------------------------------
// DGCNN-like model on MI355X, fp32 (CDNA4 has no fp32 MFMA -> VALU GEMMs).
// Pipeline:
//   knn1 (3-dim, exact, k=10) -> idx1
//   pre1: v1[m]=w1a.p, u1[n]=(w1b-w1a).p        (edge conv decomposition)
//   edge1: h1=mish(bn(v1[m]+u1[n])); h2=mish(bn(W2 h1)); x1=max_k  -> cat[:,0:64], xx2
//   pre3 GEMM: [v3|u3] = x1 @ w3stack^T
//   knn2 (64-dim exact, thread-per-row, chunked) + merge -> idx2
//   edge2: like edge1 with W4 -> x2 -> cat[:,64:128]
//   GEMM6: mish(bn(cat@w6^T)) -> column max only (flipped-uint atomics)
//   bias7: per-batch bias = (w7[:, :1024]@gmax)*s7 + sh7
//   GEMM7: mish(cat@w7x^T * s7 + bias7) -> h7
//   GEMM8: mish(bn(h7@w8^T)) -> h8
//   out:   h8@w9^T -> [B,2,N]
// ---------------------------------------------------------------------------

#define BN_EPS 1e-5f

__device__ __forceinline__ float mish_f(float x) {
  // mish(x) = x*tanh(softplus(x)) = x*(e^2+2e)/(e^2+2e+2), e=exp(x)
  float e = __expf(x);
  float num = e * (e + 2.0f);
  float r = x * (num / (num + 2.0f));
  return (x > 44.0f) ? x : r;   // guard e^2 overflow; below 44 exact formula
}

__device__ __forceinline__ float rl_f(float v, int l) {
  return __uint_as_float((unsigned)__builtin_amdgcn_readlane((int)__float_as_uint(v), l));
}

// monotonic float<->uint encode for atomicMax on possibly-negative floats
__device__ __forceinline__ unsigned enc_f(float f) {
  unsigned b = __float_as_uint(f);
  return (b & 0x80000000u) ? ~b : (b | 0x80000000u);
}
__device__ __forceinline__ float dec_f(unsigned u) {
  unsigned b = (u & 0x80000000u) ? (u ^ 0x80000000u) : ~u;
  return __uint_as_float(b);
}

// sorted-descending top-10 insertion; ties keep earlier (smaller) index first.
__device__ __forceinline__ void topk_insert(float (&v)[10], int (&id)[10], float nd, int m) {
  if (nd > v[9]) {
    v[9] = nd; id[9] = m;
#pragma unroll
    for (int j = 9; j > 0; --j) {
      if (v[j] > v[j - 1]) {
        float tv = v[j]; v[j] = v[j - 1]; v[j - 1] = tv;
        int ti = id[j]; id[j] = id[j - 1]; id[j - 1] = ti;
      }
    }
  }
}

// ---------------------------------------------------------------------------
// knn1: 3-dim points, whole batch point cloud in LDS. 64 rows/block, each row
// handled by a quad (4 lanes), each sub-lane scans 1024 candidates, then
// quad-merge of sorted lists via shfl_xor(1,2).
// ---------------------------------------------------------------------------
__global__ __launch_bounds__(256) void knn1_k(const float* __restrict__ x, int* __restrict__ idx1) {
  __shared__ float pls[3][4100];  // 4 chunks of 1025 (pad breaks bank aliasing)
  const int tid = threadIdx.x;
  const int rowBase = blockIdx.x * 64;
  const int b = rowBase >> 12;
  const float* xb = x + (size_t)b * 3 * 4096;
#pragma unroll
  for (int c = 0; c < 3; ++c) {
#pragma unroll
    for (int s = 0; s < 16; ++s) {
      int li = tid + 256 * s;
      pls[c][(li >> 10) * 1025 + (li & 1023)] = xb[c * 4096 + li];
    }
  }
  __syncthreads();
  const int sub = tid & 3;
  const int nloc = (rowBase & 4095) + (tid >> 2);
  float pnx = xb[nloc], pny = xb[4096 + nloc], pnz = xb[8192 + nloc];
  float xxn = pnx * pnx; xxn = fmaf(pny, pny, xxn); xxn = fmaf(pnz, pnz, xxn);
  float v[10]; int id[10];
#pragma unroll
  for (int j = 0; j < 10; ++j) { v[j] = -FLT_MAX; id[j] = -1; }
  const int base = sub * 1025;
  for (int i = 0; i < 1024; ++i) {
    float mx = pls[0][base + i], my = pls[1][base + i], mz = pls[2][base + i];
    float in = mx * pnx; in = fmaf(my, pny, in); in = fmaf(mz, pnz, in);
    float xm = mx * mx;  xm = fmaf(my, my, xm);  xm = fmaf(mz, mz, xm);
    float nd = 2.0f * in - xxn - xm;   // == 0 exactly for self (same fma chains)
    topk_insert(v, id, nd, sub * 1024 + i);
  }
  int k0 = -1, k1 = -1, k2 = -1;
#pragma unroll
  for (int r = 0; r < 10; ++r) {
    float mv = v[0]; int mi = id[0];
    { float ov = __shfl_xor(mv, 1); int oi = __shfl_xor(mi, 1);
      if (ov > mv || (ov == mv && oi < mi)) { mv = ov; mi = oi; } }
    { float ov = __shfl_xor(mv, 2); int oi = __shfl_xor(mi, 2);
      if (ov > mv || (ov == mv && oi < mi)) { mv = ov; mi = oi; } }
    if (id[0] == mi) {
#pragma unroll
      for (int j = 0; j < 9; ++j) { v[j] = v[j + 1]; id[j] = id[j + 1]; }
      v[9] = -FLT_MAX; id[9] = -1;
    }
    if ((r & 3) == sub) { if (r < 4) k0 = mi; else if (r < 8) k1 = mi; else k2 = mi; }
  }
  const int obase = (rowBase + (tid >> 2)) * 10;
  if (sub == 0)      { idx1[obase + 0] = k0; idx1[obase + 4] = k1; idx1[obase + 8] = k2; }
  else if (sub == 1) { idx1[obase + 1] = k0; idx1[obase + 5] = k1; idx1[obase + 9] = k2; }
  else if (sub == 2) { idx1[obase + 2] = k0; idx1[obase + 6] = k1; }
  else               { idx1[obase + 3] = k0; idx1[obase + 7] = k1; }
}

// ---------------------------------------------------------------------------
// pre1: per-point v1[m][c] = w1a[c].p,  u1[n][c] = (w1b[c]-w1a[c]).p
// ---------------------------------------------------------------------------
__global__ __launch_bounds__(256) void pre1_k(const float* __restrict__ x, const float* __restrict__ w1,
                                              float* __restrict__ e1m, float* __restrict__ e1n) {
  int gt = blockIdx.x * 256 + threadIdx.x;
  int pt = gt >> 6, c = gt & 63;
  int b = pt >> 12, n = pt & 4095;
  const float* xb = x + (size_t)b * 3 * 4096;
  float px = xb[n], py = xb[4096 + n], pz = xb[8192 + n];
  const float* wr = w1 + c * 6;
  float a0 = wr[0], a1 = wr[1], a2 = wr[2], b0 = wr[3], b1 = wr[4], b2 = wr[5];
  float vm = a0 * px; vm = fmaf(a1, py, vm); vm = fmaf(a2, pz, vm);
  float un = (b0 - a0) * px; un = fmaf(b1 - a1, py, un); un = fmaf(b2 - a2, pz, un);
  e1m[(size_t)pt * 64 + c] = vm;
  e1n[(size_t)pt * 64 + c] = un;
}

// ---------------------------------------------------------------------------
// edge conv: per wave one row; lane = output channel.
// ---------------------------------------------------------------------------
template <bool WRITE_XX>
__global__ __launch_bounds__(256) void edge_k(
    const int* __restrict__ idx,
    const float* __restrict__ vm, const float* __restrict__ un, int stride,
    const float* __restrict__ w,
    const float* __restrict__ ga, const float* __restrict__ ba, const float* __restrict__ ma, const float* __restrict__ va,
    const float* __restrict__ gb, const float* __restrict__ bb, const float* __restrict__ mb, const float* __restrict__ vb,
    float* __restrict__ outCat, int outOff, float* __restrict__ xxOut) {
  const int tid = threadIdx.x;
  const int wid = tid >> 6, lane = tid & 63;
  const int r = blockIdx.x * 4 + wid;
  const int mbase = (r >> 12) << 12;
  float4 wv[16];
  const float4* wp = (const float4*)(w + lane * 64);
#pragma unroll
  for (int i = 0; i < 16; ++i) wv[i] = wp[i];
  float s1 = ga[lane] * rsqrtf(va[lane] + BN_EPS); float t1 = ba[lane] - ma[lane] * s1;
  float s2 = gb[lane] * rsqrtf(vb[lane] + BN_EPS); float t2 = bb[lane] - mb[lane] * s2;
  float uc = un[(size_t)r * stride + lane];
  float best = -FLT_MAX;
#pragma unroll
  for (int kk = 0; kk < 10; ++kk) {
    int m = idx[r * 10 + kk];
    float pre = vm[(size_t)(mbase + m) * stride + lane] + uc;
    float h1 = mish_f(fmaf(pre, s1, t1));
    float acc = 0.f;
#pragma unroll
    for (int j4 = 0; j4 < 16; ++j4) {
      float4 wq = wv[j4];
      acc = fmaf(wq.x, rl_f(h1, 4 * j4 + 0), acc);
      acc = fmaf(wq.y, rl_f(h1, 4 * j4 + 1), acc);
      acc = fmaf(wq.z, rl_f(h1, 4 * j4 + 2), acc);
      acc = fmaf(wq.w, rl_f(h1, 4 * j4 + 3), acc);
    }
    float h2 = mish_f(fmaf(acc, s2, t2));
    best = fmaxf(best, h2);
  }
  outCat[(size_t)r * 128 + outOff + lane] = best;
  if (WRITE_XX) {
    float q = best * best;
#pragma unroll
    for (int o = 1; o < 64; o <<= 1) q += __shfl_xor(q, o);
    if (lane == 0) xxOut[r] = q;
  }
}

// ---------------------------------------------------------------------------
// knn2 v2: thread-per-row, candidates broadcast from LDS (uniform address ->
// no bank pressure, no per-lane candidate regs). Query row in 64 VGPRs,
// top-10 in 20 regs -> no scratch spills (v1 spilled 133 MB).
// Grid: (64 rowgroups of 256 rows) x (16 chunks of 256 candidates).
// Partial top-10 per (chunk,row) -> merged by knn2m_k.
// ---------------------------------------------------------------------------
#define KNN2_CHUNKS 16
__global__ __launch_bounds__(256, 4) void knn2_k(const float* __restrict__ cat,
                                                 const float* __restrict__ xx2,
                                                 float* __restrict__ pv, int* __restrict__ pi) {
  __shared__ float tile[128 * 68];   // 128 candidates, row stride 68 (write-bank spread)
  __shared__ float xxm[128];
  const int tid = threadIdx.x;
  const int r = blockIdx.x * 256 + tid;       // global query row (whole block same batch)
  const int nbase = (r >> 12) << 12;          // batch base
  const int cb = blockIdx.y * 256;            // chunk base (batch-local)
  float4 q[16];
  const float4* qp = (const float4*)(cat + (size_t)r * 128);
#pragma unroll
  for (int s = 0; s < 16; ++s) q[s] = qp[s];
  const float xxA = xx2[r];
  float v[10]; int id[10];
#pragma unroll
  for (int j = 0; j < 10; ++j) { v[j] = -FLT_MAX; id[j] = -1; }
  for (int t = 0; t < 2; ++t) {
    __syncthreads();
    {
      const int m = tid >> 1, h = tid & 1;
      const float4* src = (const float4*)(cat + (size_t)(nbase + cb + t * 128 + m) * 128) + h * 8;
      float4* dst = (float4*)(tile + m * 68) + h * 8;
#pragma unroll
      for (int s = 0; s < 8; ++s) dst[s] = src[s];
      if (tid < 128) xxm[tid] = xx2[nbase + cb + t * 128 + tid];
    }
    __syncthreads();
    for (int m = 0; m < 128; ++m) {
      const float4* crow = (const float4*)(tile + m * 68);  // uniform -> broadcast reads
      float a0 = 0.f, a1 = 0.f, a2 = 0.f, a3 = 0.f;
#pragma unroll
      for (int c4 = 0; c4 < 16; c4 += 4) {
        float4 t0 = crow[c4 + 0], t1 = crow[c4 + 1], t2 = crow[c4 + 2], t3 = crow[c4 + 3];
        a0 = fmaf(t0.x, q[c4 + 0].x, a0); a0 = fmaf(t0.y, q[c4 + 0].y, a0);
        a0 = fmaf(t0.z, q[c4 + 0].z, a0); a0 = fmaf(t0.w, q[c4 + 0].w, a0);
        a1 = fmaf(t1.x, q[c4 + 1].x, a1); a1 = fmaf(t1.y, q[c4 + 1].y, a1);
        a1 = fmaf(t1.z, q[c4 + 1].z, a1); a1 = fmaf(t1.w, q[c4 + 1].w, a1);
        a2 = fmaf(t2.x, q[c4 + 2].x, a2); a2 = fmaf(t2.y, q[c4 + 2].y, a2);
        a2 = fmaf(t2.z, q[c4 + 2].z, a2); a2 = fmaf(t2.w, q[c4 + 2].w, a2);
        a3 = fmaf(t3.x, q[c4 + 3].x, a3); a3 = fmaf(t3.y, q[c4 + 3].y, a3);
        a3 = fmaf(t3.z, q[c4 + 3].z, a3); a3 = fmaf(t3.w, q[c4 + 3].w, a3);
      }
      float nd = 2.0f * ((a0 + a1) + (a2 + a3)) - xxA - xxm[m];
      topk_insert(v, id, nd, cb + t * 128 + m);
    }
  }
  const size_t ob = ((size_t)blockIdx.y * 16384 + r) * 10;
#pragma unroll
  for (int j = 0; j < 10; ++j) { pv[ob + j] = v[j]; pi[ob + j] = id[j]; }
}

// merge 16 sorted-desc partial lists per row -> final top-10 indices.
// stability: chunks ascending (ascending candidate idx), strict-compare insert.
__global__ __launch_bounds__(256) void knn2m_k(const float* __restrict__ pv,
                                               const int* __restrict__ pi,
                                               int* __restrict__ idx2) {
  const int r = blockIdx.x * 256 + threadIdx.x;
  float v[10]; int id[10];
#pragma unroll
  for (int j = 0; j < 10; ++j) { v[j] = -FLT_MAX; id[j] = -1; }
  for (int c = 0; c < KNN2_CHUNKS; ++c) {
    const size_t base = ((size_t)c * 16384 + r) * 10;
    if (pv[base] > v[9]) {
#pragma unroll
      for (int j = 0; j < 10; ++j) topk_insert(v, id, pv[base + j], pi[base + j]);
    }
  }
#pragma unroll
  for (int j = 0; j < 10; ++j) idx2[r * 10 + j] = id[j];
}

// ---------------------------------------------------------------------------
// w3stack: rows 0..63 = w3[:, :64]; rows 64..127 = w3[:, 64:] - w3[:, :64]
// ---------------------------------------------------------------------------
__global__ void w3s_k(const float* __restrict__ w3, float* __restrict__ w3s) {
  int t = blockIdx.x * 256 + threadIdx.x;  // 0..8191
  int c = t >> 6, k = t & 63;
  float v;
  if (c < 64) v = w3[c * 128 + k];
  else { int cc = c - 64; v = w3[cc * 128 + 64 + k] - w3[cc * 128 + k]; }
  w3s[t] = v;
}

// ---------------------------------------------------------------------------
// fp32 VALU GEMM:  C[M][N] = epi(A[M][lda(:K)] @ W[N][ldw(:K)]^T)
// BM=64*QM, BN=64*QN, BK=16; 256 threads; per-thread (4*QM)x(4*QN) microtile.
// EPI: 0 raw store | 1 bn+mish store | 2 bn+mish column-max (no store)
//    | 3 scale*acc + per-batch bias + mish store
// ---------------------------------------------------------------------------
template <int QM, int QN, int EPI>
__global__ __launch_bounds__(256) void gemm_k(
    const float* __restrict__ A, int lda,
    const float* __restrict__ W, int ldw,
    float* __restrict__ C, int ldc, int K, int Ntot,
    const float* __restrict__ eg, const float* __restrict__ eb,
    const float* __restrict__ em, const float* __restrict__ ev,
    const float* __restrict__ pbBias, unsigned int* __restrict__ gmaxOut) {
  constexpr int BM = 64 * QM, BN = 64 * QN;
  __shared__ float aL[16][BM];
  __shared__ float bL[16][BN];
  __shared__ unsigned int cm[BN];
  const int tid = threadIdx.x;
  const int tm = tid >> 4, tn = tid & 15;
  const int rowBase = blockIdx.x * BM;
  const int colBase = blockIdx.y * BN;
  float acc[QM][QN][4][4] = {};
  if (EPI == 2 && tid < BN) cm[tid] = 0u;
  const int nkt = K >> 4;
  for (int kt = 0; kt < nkt; ++kt) {
#pragma unroll
    for (int s = 0; s < QM; ++s) {
      int fi = tid + 256 * s;
      int m = fi >> 2, k4 = fi & 3;
      float4 t4 = *(const float4*)(A + (size_t)(rowBase + m) * lda + (kt << 4) + k4 * 4);
      aL[k4 * 4 + 0][m] = t4.x; aL[k4 * 4 + 1][m] = t4.y;
      aL[k4 * 4 + 2][m] = t4.z; aL[k4 * 4 + 3][m] = t4.w;
    }
#pragma unroll
    for (int s = 0; s < QN; ++s) {
      int fi = tid + 256 * s;
      int n = fi >> 2, k4 = fi & 3;
      float4 t4 = *(const float4*)(W + (size_t)(colBase + n) * ldw + (kt << 4) + k4 * 4);
      bL[k4 * 4 + 0][n] = t4.x; bL[k4 * 4 + 1][n] = t4.y;
      bL[k4 * 4 + 2][n] = t4.z; bL[k4 * 4 + 3][n] = t4.w;
    }
    __syncthreads();
#pragma unroll
    for (int k = 0; k < 16; ++k) {
      float ar[QM][4], br[QN][4];
#pragma unroll
      for (int q = 0; q < QM; ++q) {
        float4 t4 = *(const float4*)&aL[k][q * 64 + tm * 4];
        ar[q][0] = t4.x; ar[q][1] = t4.y; ar[q][2] = t4.z; ar[q][3] = t4.w;
      }
#pragma unroll
      for (int q = 0; q < QN; ++q) {
        float4 t4 = *(const float4*)&bL[k][q * 64 + tn * 4];
        br[q][0] = t4.x; br[q][1] = t4.y; br[q][2] = t4.z; br[q][3] = t4.w;
      }
#pragma unroll
      for (int qm = 0; qm < QM; ++qm)
#pragma unroll
        for (int qn = 0; qn < QN; ++qn)
#pragma unroll
          for (int i = 0; i < 4; ++i)
#pragma unroll
            for (int j = 0; j < 4; ++j)
              acc[qm][qn][i][j] = fmaf(ar[qm][i], br[qn][j], acc[qm][qn][i][j]);
    }
    __syncthreads();
  }
  if (EPI == 0) {
#pragma unroll
    for (int qm = 0; qm < QM; ++qm)
#pragma unroll
      for (int i = 0; i < 4; ++i) {
        int row = rowBase + qm * 64 + tm * 4 + i;
#pragma unroll
        for (int qn = 0; qn < QN; ++qn) {
          float4 o;
          o.x = acc[qm][qn][i][0]; o.y = acc[qm][qn][i][1];
          o.z = acc[qm][qn][i][2]; o.w = acc[qm][qn][i][3];
          *(float4*)(C + (size_t)row * ldc + colBase + qn * 64 + tn * 4) = o;
        }
      }
  } else {
    const int bidx = rowBase >> 12;
    float sc[QN][4], sh[QN][4];
#pragma unroll
    for (int qn = 0; qn < QN; ++qn)
#pragma unroll
      for (int j = 0; j < 4; ++j) {
        int cg = colBase + qn * 64 + tn * 4 + j;
        float s = eg[cg] * rsqrtf(ev[cg] + BN_EPS);
        sc[qn][j] = s;
        sh[qn][j] = (EPI == 3) ? pbBias[bidx * Ntot + cg] : (eb[cg] - em[cg] * s);
      }
    if (EPI == 2) {
      float cmax[QN][4];
#pragma unroll
      for (int qn = 0; qn < QN; ++qn)
#pragma unroll
        for (int j = 0; j < 4; ++j) cmax[qn][j] = -FLT_MAX;
#pragma unroll
      for (int qm = 0; qm < QM; ++qm)
#pragma unroll
        for (int qn = 0; qn < QN; ++qn)
#pragma unroll
          for (int i = 0; i < 4; ++i)
#pragma unroll
            for (int j = 0; j < 4; ++j) {
              float vv = mish_f(fmaf(acc[qm][qn][i][j], sc[qn][j], sh[qn][j]));
              cmax[qn][j] = fmaxf(cmax[qn][j], vv);
            }
#pragma unroll
      for (int qn = 0; qn < QN; ++qn)
#pragma unroll
        for (int j = 0; j < 4; ++j)
          atomicMax(&cm[qn * 64 + tn * 4 + j], enc_f(cmax[qn][j]));
      __syncthreads();
      if (tid < BN) atomicMax(&gmaxOut[bidx * Ntot + colBase + tid], cm[tid]);
    } else {
#pragma unroll
      for (int qm = 0; qm < QM; ++qm)
#pragma unroll
        for (int i = 0; i < 4; ++i) {
          int row = rowBase + qm * 64 + tm * 4 + i;
#pragma unroll
          for (int qn = 0; qn < QN; ++qn) {
            float4 o;
            o.x = mish_f(fmaf(acc[qm][qn][i][0], sc[qn][0], sh[qn][0]));
            o.y = mish_f(fmaf(acc[qm][qn][i][1], sc[qn][1], sh[qn][1]));
            o.z = mish_f(fmaf(acc[qm][qn][i][2], sc[qn][2], sh[qn][2]));
            o.w = mish_f(fmaf(acc[qm][qn][i][3], sc[qn][3], sh[qn][3]));
            *(float4*)(C + (size_t)row * ldc + colBase + qn * 64 + tn * 4) = o;
          }
        }
    }
  }
}

// ---------------------------------------------------------------------------
// bias7: per-batch channel bias = (w7[:, :1024] @ gmax[b])*s7 + sh7
// ---------------------------------------------------------------------------
__global__ __launch_bounds__(256) void bias7_k(const unsigned int* __restrict__ gmaxU,
                                               const float* __restrict__ w7,
                                               const float* __restrict__ g7, const float* __restrict__ b7,
                                               const float* __restrict__ m7, const float* __restrict__ v7,
                                               float* __restrict__ bias7) {
  __shared__ float gl[1024];
  const int tid = threadIdx.x;
  const int batch = blockIdx.x >> 1, half = blockIdx.x & 1;
#pragma unroll
  for (int s = 0; s < 4; ++s) gl[tid + 256 * s] = dec_f(gmaxU[batch * 1024 + tid + 256 * s]);
  __syncthreads();
  const int ch = half * 256 + tid;
  const float4* wr = (const float4*)(w7 + (size_t)ch * 1152);
  float acc = 0.f;
  for (int j4 = 0; j4 < 256; ++j4) {
    float4 w = wr[j4];
    float4 g = *(const float4*)&gl[j4 * 4];
    acc = fmaf(w.x, g.x, acc); acc = fmaf(w.y, g.y, acc);
    acc = fmaf(w.z, g.z, acc); acc = fmaf(w.w, g.w, acc);
  }
  float s7 = g7[ch] * rsqrtf(v7[ch] + BN_EPS);
  bias7[batch * 512 + ch] = acc * s7 + (b7[ch] - m7[ch] * s7);
}

// ---------------------------------------------------------------------------
// out: out[b][o][n] = sum_c h8[row][c]*w9[o][c]
// ---------------------------------------------------------------------------
__global__ __launch_bounds__(256) void out_k(const float* __restrict__ h8,
                                             const float* __restrict__ w9, float* __restrict__ out) {
  __shared__ float w9l[512];
  const int tid = threadIdx.x;
  w9l[tid] = w9[tid];
  w9l[256 + tid] = w9[256 + tid];
  __syncthreads();
  const int t = blockIdx.x * 256 + tid;
  const int b = t >> 12, n = t & 4095;
  const float4* hr = (const float4*)(h8 + (size_t)t * 256);
  float a0 = 0.f, a1 = 0.f;
#pragma unroll
  for (int j4 = 0; j4 < 64; ++j4) {
    float4 h = hr[j4];
    float4 wa = *(const float4*)&w9l[j4 * 4];
    float4 wb = *(const float4*)&w9l[256 + j4 * 4];
    a0 = fmaf(h.x, wa.x, a0); a0 = fmaf(h.y, wa.y, a0);
    a0 = fmaf(h.z, wa.z, a0); a0 = fmaf(h.w, wa.w, a0);
    a1 = fmaf(h.x, wb.x, a1); a1 = fmaf(h.y, wb.y, a1);
    a1 = fmaf(h.z, wb.z, a1); a1 = fmaf(h.w, wb.w, a1);
  }
  out[(size_t)b * 8192 + n] = a0;
  out[(size_t)b * 8192 + 4096 + n] = a1;
}

// ---------------------------------------------------------------------------
extern "C" void kernel_launch(void* const* d_in, const int* in_sizes, int n_in,
                              void* d_out, int out_size, void* d_ws, size_t ws_size,
                              hipStream_t stream) {
  const float* x  = (const float*)d_in[0];
  const float* w1 = (const float*)d_in[1];
  const float* g1 = (const float*)d_in[2];
  const float* b1 = (const float*)d_in[3];
  const float* m1 = (const float*)d_in[4];
  const float* v1 = (const float*)d_in[5];
  const float* w2 = (const float*)d_in[6];
  const float* g2 = (const float*)d_in[7];
  const float* b2 = (const float*)d_in[8];
  const float* m2 = (const float*)d_in[9];
  const float* v2 = (const float*)d_in[10];
  const float* w3 = (const float*)d_in[11];
  const float* g3 = (const float*)d_in[12];
  const float* b3 = (const float*)d_in[13];
  const float* m3 = (const float*)d_in[14];
  const float* v3 = (const float*)d_in[15];
  const float* w4 = (const float*)d_in[16];
  const float* g4 = (const float*)d_in[17];
  const float* b4 = (const float*)d_in[18];
  const float* m4 = (const float*)d_in[19];
  const float* v4 = (const float*)d_in[20];
  const float* w6 = (const float*)d_in[21];
  const float* g6 = (const float*)d_in[22];
  const float* b6 = (const float*)d_in[23];
  const float* m6 = (const float*)d_in[24];
  const float* v6 = (const float*)d_in[25];
  const float* w7 = (const float*)d_in[26];
  const float* g7 = (const float*)d_in[27];
  const float* b7 = (const float*)d_in[28];
  const float* m7 = (const float*)d_in[29];
  const float* v7 = (const float*)d_in[30];
  const float* w8 = (const float*)d_in[31];
  const float* g8 = (const float*)d_in[32];
  const float* b8 = (const float*)d_in[33];
  const float* m8 = (const float*)d_in[34];
  const float* v8 = (const float*)d_in[35];
  const float* w9 = (const float*)d_in[36];

  float* ws = (float*)d_ws;
  // element offsets (all multiples of 4 -> 16B aligned)
  int* idx1       = (int*)(ws + 0);          //   163840
  int* idx2       = (int*)(ws + 163840);     //   163840
  float* xx2      = ws + 327680;             //    16384
  unsigned* gmax  = (unsigned*)(ws + 344064);//     4096
  float* bias7    = ws + 348160;             //     2048
  float* w3s      = ws + 350208;             //     8192
  float* e1n      = ws + 358400;             //  1048576
  float* e1m      = ws + 1406976;            //  1048576
  float* pre3     = ws + 358400;             //  2097152 (aliases e1n/e1m; written after edge1)
  float* cat      = ws + 2455552;            //  2097152
  float* h7       = ws + 4552704;            //  8388608
  float* h8       = ws + 12941312;           //  4194304  (end: 17135616 floats = 68.5 MB)
  // knn2 partials alias h7 (consumed by knn2m before gemm7 writes h7):
  float* knn2pv   = h7;                      //  2621440
  int*   knn2pi   = (int*)(h7 + 2621440);    //  2621440

  hipMemsetAsync(gmax, 0, 4096 * sizeof(unsigned), stream);

  knn1_k<<<256, 256, 0, stream>>>(x, idx1);
  pre1_k<<<4096, 256, 0, stream>>>(x, w1, e1m, e1n);
  edge_k<true><<<4096, 256, 0, stream>>>(idx1, e1m, e1n, 64, w2,
                                         g1, b1, m1, v1, g2, b2, m2, v2,
                                         cat, 0, xx2);
  w3s_k<<<32, 256, 0, stream>>>(w3, w3s);
  gemm_k<1, 2, 0><<<dim3(256, 1), 256, 0, stream>>>(cat, 128, w3s, 64, pre3, 128, 64, 0,
                                                    nullptr, nullptr, nullptr, nullptr, nullptr, nullptr);
  knn2_k<<<dim3(64, KNN2_CHUNKS), 256, 0, stream>>>(cat, xx2, knn2pv, knn2pi);
  knn2m_k<<<64, 256, 0, stream>>>(knn2pv, knn2pi, idx2);
  edge_k<false><<<4096, 256, 0, stream>>>(idx2, pre3, pre3 + 64, 128, w4,
                                          g3, b3, m3, v3, g4, b4, m4, v4,
                                          cat, 64, nullptr);
  gemm_k<2, 2, 2><<<dim3(128, 8), 256, 0, stream>>>(cat, 128, w6, 128, nullptr, 0, 128, 1024,
                                                    g6, b6, m6, v6, nullptr, gmax);
  bias7_k<<<8, 256, 0, stream>>>(gmax, w7, g7, b7, m7, v7, bias7);
  gemm_k<2, 2, 3><<<dim3(128, 4), 256, 0, stream>>>(cat, 128, w7 + 1024, 1152, h7, 512, 128, 512,
                                                    g7, nullptr, nullptr, v7, bias7, nullptr);
  gemm_k<1, 2, 1><<<dim3(256, 2), 256, 0, stream>>>(h7, 512, w8, 512, h8, 256, 512, 256,
                                                    g8, b8, m8, v8, nullptr, nullptr);
  out_k<<<64, 256, 0, stream>>>(h8, w9, (float*)d_out);
}